// Round 9
// baseline (1672.784 us; speedup 1.0000x reference)
//
#include <hip/hip_runtime.h>

#define BB 256
#define LL 65536
#define TS 1024
#define HIST 256
#define WINW 64
#define DIM 256
#define NPAT 64
#define NCH 32           // chunks per batch
#define CH 32            // timesteps per chunk
#define SLOT (CH * 64)   // shorts per ring slot

typedef short s8v __attribute__((ext_vector_type(8)));
typedef float f4v __attribute__((ext_vector_type(4)));

#define MFMA16(a, b, c) __builtin_amdgcn_mfma_f32_16x16x32_bf16((a), (b), (c), 0, 0, 0)
#define LOG2E 1.44269504f

// ---- fp32 -> bf16 hi/lo split ----
__device__ __forceinline__ short bf16rne(float f) {
    unsigned u = __float_as_uint(f);
    unsigned r = (u + 0x7fffu + ((u >> 16) & 1u)) >> 16;
    return (short)r;
}
__device__ __forceinline__ float bf16tof(short h) {
    return __uint_as_float(((unsigned)(unsigned short)h) << 16);
}
__device__ __forceinline__ void split2(float f, short& hi, short& lo) {
    hi = bf16rne(f);
    lo = bf16rne(f - bf16tof(hi));
}

// ---- merged prep: conv_w / keys / shapes -> hi/lo MFMA B-fragments ----
__global__ void prep_all(const float* __restrict__ w, short* __restrict__ wFH,
                         short* __restrict__ wFL,
                         const float* __restrict__ keys, short* __restrict__ kFH,
                         short* __restrict__ kFL,
                         const float* __restrict__ sh, short* __restrict__ sFH,
                         short* __restrict__ sFL) {
    int bid = blockIdx.x;
    s8v hv, lv;
    if (bid < 32) {
        int idx = bid * 256 + threadIdx.x;
        int d = idx & 255, qk = idx >> 8;
        int h0 = qk * 8;
#pragma unroll
        for (int j = 0; j < 8; ++j) {
            short h, l; split2(w[d * HIST + h0 + j], h, l);
            hv[j] = h; lv[j] = l;
        }
        *(s8v*)(wFH + (size_t)idx * 8) = hv;
        *(s8v*)(wFL + (size_t)idx * 8) = lv;
    } else if (bid < 40) {
        int idx = (bid - 32) * 256 + threadIdx.x;
        int p = idx & 63, qk = idx >> 6;
        int d0 = qk * 8;
#pragma unroll
        for (int j = 0; j < 8; ++j) {
            short h, l; split2(keys[(d0 + j) * NPAT + p], h, l);
            hv[j] = h; lv[j] = l;
        }
        *(s8v*)(kFH + (size_t)idx * 8) = hv;
        *(s8v*)(kFL + (size_t)idx * 8) = lv;
    } else {
        int idx = (bid - 40) * 256 + threadIdx.x;
        int ww = idx & 63, qk = idx >> 6;
        int p0 = qk * 8;
#pragma unroll
        for (int j = 0; j < 8; ++j) {
            short h, l; split2(sh[(p0 + j) * WINW + ww], h, l);
            hv[j] = h; lv[j] = l;
        }
        *(s8v*)(sFH + (size_t)idx * 8) = hv;
        *(s8v*)(sFL + (size_t)idx * 8) = lv;
    }
}

#define WELEM 2240

__device__ __forceinline__ int swz(int u) { return u ^ ((u >> 3) & 7); }

template <int CTRL>
__device__ __forceinline__ float dppadd(float x) {
    int t = __builtin_amdgcn_update_dpp(0, __float_as_int(x), CTRL, 0xf, 0xf, true);
    return x + __int_as_float(t);
}

// ---- cheap dual-flag wait: lane-0 poll, readfirstlane broadcast, long backoff ----
// (R7 lesson: 64-lane atomic spin = fabric storm. One lane @ ~0.85us period is free.)
__device__ __forceinline__ void wait2(unsigned* fA, unsigned* fB, int lane) {
    for (;;) {
        unsigned a = 1u, b = 1u;
        if (lane == 0) {
            a = __hip_atomic_load(fA, __ATOMIC_RELAXED, __HIP_MEMORY_SCOPE_AGENT);
            b = __hip_atomic_load(fB, __ATOMIC_RELAXED, __HIP_MEMORY_SCOPE_AGENT);
        }
        unsigned ok = __builtin_amdgcn_readfirstlane((a & b) != 0u ? 1u : 0u);
        if (ok) break;
        __builtin_amdgcn_s_sleep(32);
    }
    __builtin_amdgcn_fence(__ATOMIC_ACQUIRE, "agent");
}

// ================= scores role (R2-measured body + publish) =================
__device__ __forceinline__ void scores_role(short* smem, int b, int t0,
        const float* __restrict__ x,
        const short* __restrict__ wFH, const short* __restrict__ wFL,
        const short* __restrict__ kFH, const short* __restrict__ kFL,
        const float* __restrict__ conv_b,
        float* __restrict__ scoresT, unsigned* __restrict__ flags) {
    short* hidH = smem;
    short* hidL = smem + 8192;
    short* xsH = hidH;
    short* xsL = hidL;

    const int tid = threadIdx.x;
    const int lane = tid & 63, wid = tid >> 6;
    const int m = lane & 15, q = lane >> 4;

    const float* xb = x + (size_t)b * LL;
    const int gbase = t0 * WINW - (HIST - 1);
    for (int i = tid; i < WELEM; i += 256) {
        int gi = gbase + i;
        float v = (gi >= 0) ? xb[gi] : 0.0f;
        short h, l; split2(v, h, l);
        int pos = (swz(i >> 3) << 3) | (i & 7);
        xsH[pos] = h; xsL[pos] = l;
    }
    __syncthreads();

    const int nb = wid * 64;
    f4v acc[2][4];
#pragma unroll
    for (int mt = 0; mt < 2; ++mt)
#pragma unroll
        for (int nt = 0; nt < 4; ++nt) acc[mt][nt] = (f4v)0.0f;

    for (int kt = 0; kt < 8; ++kt) {
        s8v aH[2], aL[2];
#pragma unroll
        for (int mt = 0; mt < 2; ++mt) {
            int row = mt * 16 + m;
            int su = swz(row * 8 + kt * 4 + q) << 3;
            aH[mt] = *(const s8v*)&xsH[su];
            aL[mt] = *(const s8v*)&xsL[su];
        }
        s8v bH[4], bL[4];
#pragma unroll
        for (int nt = 0; nt < 4; ++nt) {
            size_t bi = ((size_t)(kt * 4 + q) * 256 + nb + nt * 16 + m) * 8;
            bH[nt] = *(const s8v*)(wFH + bi);
            bL[nt] = *(const s8v*)(wFL + bi);
        }
#pragma unroll
        for (int mt = 0; mt < 2; ++mt)
#pragma unroll
            for (int nt = 0; nt < 4; ++nt)
                acc[mt][nt] = MFMA16(aH[mt], bH[nt], acc[mt][nt]);
#pragma unroll
        for (int mt = 0; mt < 2; ++mt)
#pragma unroll
            for (int nt = 0; nt < 4; ++nt)
                acc[mt][nt] = MFMA16(aL[mt], bH[nt], acc[mt][nt]);
#pragma unroll
        for (int mt = 0; mt < 2; ++mt)
#pragma unroll
            for (int nt = 0; nt < 4; ++nt)
                acc[mt][nt] = MFMA16(aH[mt], bL[nt], acc[mt][nt]);
    }
    __syncthreads();

#pragma unroll
    for (int mt = 0; mt < 2; ++mt)
#pragma unroll
        for (int nt = 0; nt < 4; ++nt) {
            int d = nb + nt * 16 + m;
            float bias = conv_b[d];
#pragma unroll
            for (int r = 0; r < 4; ++r) {
                int row = mt * 16 + q * 4 + r;
                float v = fmaxf(acc[mt][nt][r] + bias, 0.0f);
                short h, l; split2(v, h, l);
                int dd = d ^ ((row & 7) << 3);
                hidH[row * 256 + dd] = h;
                hidL[row * 256 + dd] = l;
            }
        }
    __syncthreads();

    const int pb = wid * 16;
    const int sw0 = (m & 7) << 3;
    f4v aHH[2], aLH[2], aHL[2];
#pragma unroll
    for (int mt = 0; mt < 2; ++mt) {
        aHH[mt] = (f4v)0.0f; aLH[mt] = (f4v)0.0f; aHL[mt] = (f4v)0.0f;
    }
    for (int kt = 0; kt < 8; ++kt) {
        s8v aH[2], aL[2];
#pragma unroll
        for (int mt = 0; mt < 2; ++mt) {
            int off = (mt * 16 + m) * 256 + ((kt * 32 + q * 8) ^ sw0);
            aH[mt] = *(const s8v*)&hidH[off];
            aL[mt] = *(const s8v*)&hidL[off];
        }
        size_t bi = ((size_t)(kt * 4 + q) * 64 + pb + m) * 8;
        s8v bH = *(const s8v*)(kFH + bi);
        s8v bL = *(const s8v*)(kFL + bi);
#pragma unroll
        for (int mt = 0; mt < 2; ++mt)
            aHH[mt] = MFMA16(aH[mt], bH, aHH[mt]);
#pragma unroll
        for (int mt = 0; mt < 2; ++mt)
            aLH[mt] = MFMA16(aL[mt], bH, aLH[mt]);
#pragma unroll
        for (int mt = 0; mt < 2; ++mt)
            aHL[mt] = MFMA16(aH[mt], bL, aHL[mt]);
    }
#pragma unroll
    for (int mt = 0; mt < 2; ++mt) {
        f4v s = aHH[mt] + aLH[mt] + aHL[mt];
        float4 st;
        st.x = fminf(fmaxf(s[0], 0.0f), 6.0f) * LOG2E;
        st.y = fminf(fmaxf(s[1], 0.0f), 6.0f) * LOG2E;
        st.z = fminf(fmaxf(s[2], 0.0f), 6.0f) * LOG2E;
        st.w = fminf(fmaxf(s[3], 0.0f), 6.0f) * LOG2E;
        *(float4*)&scoresT[((size_t)b * NPAT + pb + m) * TS + t0 + mt * 16 + q * 4] = st;
    }
    __threadfence();
    __syncthreads();
    if (tid == 0)
        __hip_atomic_store(&flags[b * NCH + (t0 >> 5)], 1u,
                           __ATOMIC_RELEASE, __HIP_MEMORY_SCOPE_AGENT);
}

// ================= mixed grid: 128 scan/signal blocks + 8192 scores blocks ====
// scan blocks first (1/CU), R8's dual-chain + 2 consumers + barrier-matcher wave.
// scores in tb-major order so every batch's chunk c publishes early.
__launch_bounds__(256, 4)
__global__ void fused(const float* __restrict__ x,
                      const short* __restrict__ wFH, const short* __restrict__ wFL,
                      const short* __restrict__ kFH, const short* __restrict__ kFL,
                      const short* __restrict__ sFH, const short* __restrict__ sFL,
                      const float* __restrict__ conv_b,
                      const float* __restrict__ avg0,
                      float* __restrict__ scoresT,
                      unsigned* __restrict__ flags,
                      float* __restrict__ out) {
    __shared__ __align__(16) short smem[16384];    // 32 KB, both roles

    if (blockIdx.x >= 128) {
        const int sid = blockIdx.x - 128;
        const int tb = sid >> 8;           // tb-major: all batches' tb=0 first
        const int b = sid & 255;
        scores_role(smem, b, tb * 32, x, wFH, wFL, kFH, kFL, conv_b, scoresT, flags);
        return;
    }

    const int blk = blockIdx.x;            // 0..127
    const int bA = 2 * blk, bB = 2 * blk + 1;
    const int tid = threadIdx.x;
    const int wid = tid >> 6, lane = tid & 63;
    short* pbAH = smem;                    // [2][CH][64] each
    short* pbAL = smem + 4096;
    short* pbBH = smem + 8192;
    short* pbBL = smem + 12288;

    if (wid == 0) {
        // ---------- dual scan wave (R8 math verbatim; depth-2 prefetch) ----------
        const int p = lane;
        const float4* sA = (const float4*)(scoresT + ((size_t)bA * NPAT + p) * TS);
        const float4* sB = (const float4*)(scoresT + ((size_t)bB * NPAT + p) * TS);
        float avgA = avg0[bA * NPAT + p] * LOG2E;
        float avgB = avg0[bB * NPAT + p] * LOG2E;
        const float invc = LOG2E / NPAT;

        wait2(&flags[bA * NCH], &flags[bB * NCH], lane);
        float4 bufA[2], bufB[2];
#pragma unroll
        for (int s = 0; s < 2; ++s) { bufA[s] = sA[s]; bufB[s] = sB[s]; }

        for (int c = 0; c < NCH; ++c) {
            if (c + 1 < NCH)
                wait2(&flags[bA * NCH + c + 1], &flags[bB * NCH + c + 1], lane);
            short* bHA = pbAH + (c & 1) * SLOT;
            short* bLA = pbAL + (c & 1) * SLOT;
            short* bHB = pbBH + (c & 1) * SLOT;
            short* bLB = pbBL + (c & 1) * SLOT;
            for (int kb = 0; kb < 8; kb += 2) {
#pragma unroll
                for (int s = 0; s < 2; ++s) {
                    const int g = c * 8 + kb + s;
                    float4 vA = bufA[s], vB = bufB[s];
                    float* a = (float*)&vA;
                    float* bv = (float*)&vB;
#pragma unroll
                    for (int j = 0; j < 4; ++j) {
                        float eA = exp2f(a[j] - avgA);
                        float eB = exp2f(bv[j] - avgB);
                        float wA = eA, wB = eB;
                        wA = dppadd<0x111>(wA); wB = dppadd<0x111>(wB);
                        wA = dppadd<0x112>(wA); wB = dppadd<0x112>(wB);
                        wA = dppadd<0x114>(wA); wB = dppadd<0x114>(wB);
                        wA = dppadd<0x118>(wA); wB = dppadd<0x118>(wB);
                        wA = dppadd<0x142>(wA); wB = dppadd<0x142>(wB);
                        wA = dppadd<0x143>(wA); wB = dppadd<0x143>(wB);
                        float tA = __int_as_float(
                            __builtin_amdgcn_readlane(__float_as_int(wA), 63));
                        float tB = __int_as_float(
                            __builtin_amdgcn_readlane(__float_as_int(wB), 63));
                        float prA = eA * __builtin_amdgcn_rcpf(tA);
                        float prB = eB * __builtin_amdgcn_rcpf(tB);
                        avgA = __builtin_fmaf(prA, LOG2E, avgA - invc);
                        avgB = __builtin_fmaf(prB, LOG2E, avgB - invc);
                        const int trow = (kb + s) * 4 + j;
                        const int col = p ^ ((trow & 7) << 3);
                        short h, l;
                        split2(prA, h, l);
                        bHA[trow * 64 + col] = h;
                        bLA[trow * 64 + col] = l;
                        split2(prB, h, l);
                        bHB[trow * 64 + col] = h;
                        bLB[trow * 64 + col] = l;
                    }
                    if (g + 2 < TS / 4) {      // depth-2 refill; flag c+1 confirmed
                        bufA[s] = sA[g + 2];
                        bufB[s] = sB[g + 2];
                    }
                }
            }
            __syncthreads();   // chunk c published
        }
        __syncthreads();       // cover consumers' last chunk
    } else if (wid <= 2) {
        // ---------- signal consumer wave (one batch; sb reloaded per chunk) ----------
        const int b = (wid == 1) ? bA : bB;
        const short* rbH = (wid == 1) ? pbAH : pbBH;
        const short* rbL = (wid == 1) ? pbAL : pbBL;
        const int m = lane & 15, q = lane >> 4;
        const float* xb = x + (size_t)b * LL;
        float* ob = out + (size_t)b * LL;

        __syncthreads();       // wave 0 filling chunk 0
        for (int cc = 0; cc < NCH; ++cc) {
            const short* pH = rbH + (cc & 1) * SLOT;
            const short* pL = rbL + (cc & 1) * SLOT;
            const int t0 = cc * CH;
#pragma unroll
            for (int mt = 0; mt < 2; ++mt) {
                float xv[4][4];
#pragma unroll
                for (int nt = 0; nt < 4; ++nt)
#pragma unroll
                    for (int r = 0; r < 4; ++r)
                        xv[nt][r] = xb[(size_t)(t0 + mt * 16 + q * 4 + r) * WINW +
                                       nt * 16 + m];
                f4v acc[4];
#pragma unroll
                for (int nt = 0; nt < 4; ++nt) acc[nt] = (f4v)0.0f;
#pragma unroll
                for (int kt = 0; kt < 2; ++kt) {
                    const int rr = mt * 16 + m;
                    const int col = (kt * 32 + q * 8) ^ ((m & 7) << 3);
                    s8v aH = *(const s8v*)&pH[rr * 64 + col];
                    s8v aL = *(const s8v*)&pL[rr * 64 + col];
#pragma unroll
                    for (int nt = 0; nt < 4; ++nt) {
                        size_t bi = ((size_t)(kt * 4 + q) * 64 + nt * 16 + m) * 8;
                        s8v bH = *(const s8v*)(sFH + bi);
                        s8v bL = *(const s8v*)(sFL + bi);
                        acc[nt] = MFMA16(aH, bH, acc[nt]);
                        acc[nt] = MFMA16(aL, bH, acc[nt]);
                        acc[nt] = MFMA16(aH, bL, acc[nt]);
                    }
                }
#pragma unroll
                for (int nt = 0; nt < 4; ++nt)
#pragma unroll
                    for (int r = 0; r < 4; ++r) {
                        size_t gi = (size_t)(t0 + mt * 16 + q * 4 + r) * WINW +
                                    nt * 16 + m;
                        ob[gi] = fmaxf(acc[nt][r] - xv[nt][r], 0.0f);
                    }
            }
            __syncthreads();   // ring slot free
        }
    } else {
        // ---------- barrier matcher (wave 3): 33 barriers like the other waves ----------
        for (int i = 0; i < NCH + 1; ++i) __syncthreads();
    }
}

extern "C" void kernel_launch(void* const* d_in, const int* in_sizes, int n_in,
                              void* d_out, int out_size, void* d_ws, size_t ws_size,
                              hipStream_t stream) {
    const float* x      = (const float*)d_in[0];
    const float* avg0   = (const float*)d_in[1];
    const float* conv_w = (const float*)d_in[2];
    const float* conv_b = (const float*)d_in[3];
    const float* keys   = (const float*)d_in[4];
    const float* shapes = (const float*)d_in[5];
    float* out = (float*)d_out;

    char* ws = (char*)d_ws;
    size_t o = 0;
    float* scoresT = (float*)(ws + o); o += (size_t)BB * TS * NPAT * 4;   // 64 MB
    short* wFH = (short*)(ws + o); o += 8192 * 16;
    short* wFL = (short*)(ws + o); o += 8192 * 16;
    short* kFH = (short*)(ws + o); o += 2048 * 16;
    short* kFL = (short*)(ws + o); o += 2048 * 16;
    short* sFH = (short*)(ws + o); o += 512 * 16;
    short* sFL = (short*)(ws + o); o += 512 * 16;
    unsigned* flags = (unsigned*)(ws + o); o += (size_t)BB * NCH * 4;     // 32 KB

    hipMemsetAsync(flags, 0, (size_t)BB * NCH * 4, stream);
    prep_all<<<42, 256, 0, stream>>>(conv_w, wFH, wFL, keys, kFH, kFL, shapes, sFH, sFL);
    fused<<<dim3(128 + 32 * BB), 256, 0, stream>>>(x, wFH, wFL, kFH, kFL, sFH, sFL,
                                                   conv_b, avg0, scoresT, flags, out);
}

// Round 11
// 448.665 us; speedup vs baseline: 3.7284x; 3.7284x over previous
//
#include <hip/hip_runtime.h>

#define BB 256
#define LL 65536
#define TS 1024
#define HIST 256
#define WINW 64
#define DIM 256
#define NPAT 64
#define NCH 32           // chunks per batch
#define CH 32            // timesteps per chunk
#define SLOT (CH * 64)   // shorts per ring slot

typedef short s8v __attribute__((ext_vector_type(8)));
typedef float f4v __attribute__((ext_vector_type(4)));

#define MFMA16(a, b, c) __builtin_amdgcn_mfma_f32_16x16x32_bf16((a), (b), (c), 0, 0, 0)
#define LOG2E 1.44269504f

// ---- fp32 -> bf16 hi/lo split ----
__device__ __forceinline__ short bf16rne(float f) {
    unsigned u = __float_as_uint(f);
    unsigned r = (u + 0x7fffu + ((u >> 16) & 1u)) >> 16;
    return (short)r;
}
__device__ __forceinline__ float bf16tof(short h) {
    return __uint_as_float(((unsigned)(unsigned short)h) << 16);
}
__device__ __forceinline__ void split2(float f, short& hi, short& lo) {
    hi = bf16rne(f);
    lo = bf16rne(f - bf16tof(hi));
}

// ---- merged prep: conv_w / keys / shapes -> hi/lo MFMA B-fragments ----
__global__ void prep_all(const float* __restrict__ w, short* __restrict__ wFH,
                         short* __restrict__ wFL,
                         const float* __restrict__ keys, short* __restrict__ kFH,
                         short* __restrict__ kFL,
                         const float* __restrict__ sh, short* __restrict__ sFH,
                         short* __restrict__ sFL) {
    int bid = blockIdx.x;
    s8v hv, lv;
    if (bid < 32) {
        int idx = bid * 256 + threadIdx.x;
        int d = idx & 255, qk = idx >> 8;
        int h0 = qk * 8;
#pragma unroll
        for (int j = 0; j < 8; ++j) {
            short h, l; split2(w[d * HIST + h0 + j], h, l);
            hv[j] = h; lv[j] = l;
        }
        *(s8v*)(wFH + (size_t)idx * 8) = hv;
        *(s8v*)(wFL + (size_t)idx * 8) = lv;
    } else if (bid < 40) {
        int idx = (bid - 32) * 256 + threadIdx.x;
        int p = idx & 63, qk = idx >> 6;
        int d0 = qk * 8;
#pragma unroll
        for (int j = 0; j < 8; ++j) {
            short h, l; split2(keys[(d0 + j) * NPAT + p], h, l);
            hv[j] = h; lv[j] = l;
        }
        *(s8v*)(kFH + (size_t)idx * 8) = hv;
        *(s8v*)(kFL + (size_t)idx * 8) = lv;
    } else {
        int idx = (bid - 40) * 256 + threadIdx.x;
        int ww = idx & 63, qk = idx >> 6;
        int p0 = qk * 8;
#pragma unroll
        for (int j = 0; j < 8; ++j) {
            short h, l; split2(sh[(p0 + j) * WINW + ww], h, l);
            hv[j] = h; lv[j] = l;
        }
        *(s8v*)(sFH + (size_t)idx * 8) = hv;
        *(s8v*)(sFL + (size_t)idx * 8) = lv;
    }
}

#define WELEM 2240

__device__ __forceinline__ int swz(int u) { return u ^ ((u >> 3) & 7); }

template <int CTRL>
__device__ __forceinline__ float dppadd(float x) {
    int t = __builtin_amdgcn_update_dpp(0, __float_as_int(x), CTRL, 0xf, 0xf, true);
    return x + __int_as_float(t);
}

// ---- sc0 sc1 (system-coherent, L2-bypass) primitives: NO cache-maintenance ops ----
// R7/R9 post-mortem: agent-scope fences emit buffer_wbl2 / buffer_inv (full 4MB L2
// walks); ~1000 per XCD serialized the chip 9x. These primitives talk straight to
// the LLC so no fence is ever needed. NOTE: asm operands must be ext_vector types
// (HIP float4 is struct-wrapped -> "indirect register input" compile error, R10).
__device__ __forceinline__ void store4_llc(float* p, f4v v) {
    asm volatile("global_store_dwordx4 %0, %1, off sc0 sc1"
                 :: "v"(p), "v"(v) : "memory");
}
__device__ __forceinline__ void store1_llc(unsigned* p, unsigned v) {
    asm volatile("global_store_dword %0, %1, off sc0 sc1"
                 :: "v"(p), "v"(v) : "memory");
}
__device__ __forceinline__ void drain_stores() {
    asm volatile("s_waitcnt vmcnt(0)" ::: "memory");
}

// dual-flag wait: lane-0 sc1 poll (bypasses local L2 -> no stale-flag trap),
// readfirstlane broadcast, s_sleep backoff. No acquire fence.
__device__ __forceinline__ void wait2(const unsigned* fA, const unsigned* fB, int lane) {
    for (;;) {
        unsigned a = 1u, b = 1u;
        if (lane == 0) {
            asm volatile("global_load_dword %0, %2, off sc0 sc1\n\t"
                         "global_load_dword %1, %3, off sc0 sc1\n\t"
                         "s_waitcnt vmcnt(0)"
                         : "=&v"(a), "=&v"(b) : "v"(fA), "v"(fB) : "memory");
        }
        unsigned ok = __builtin_amdgcn_readfirstlane(((a & b) != 0u) ? 1u : 0u);
        if (ok) break;
        __builtin_amdgcn_s_sleep(8);
    }
}

// ================= scores role (R2-measured body + LLC publish) =================
__device__ __forceinline__ void scores_role(short* smem, int b, int t0,
        const float* __restrict__ x,
        const short* __restrict__ wFH, const short* __restrict__ wFL,
        const short* __restrict__ kFH, const short* __restrict__ kFL,
        const float* __restrict__ conv_b,
        float* __restrict__ scoresT, unsigned* __restrict__ flags) {
    short* hidH = smem;
    short* hidL = smem + 8192;
    short* xsH = hidH;
    short* xsL = hidL;

    const int tid = threadIdx.x;
    const int lane = tid & 63, wid = tid >> 6;
    const int m = lane & 15, q = lane >> 4;

    const float* xb = x + (size_t)b * LL;
    const int gbase = t0 * WINW - (HIST - 1);
    for (int i = tid; i < WELEM; i += 256) {
        int gi = gbase + i;
        float v = (gi >= 0) ? xb[gi] : 0.0f;
        short h, l; split2(v, h, l);
        int pos = (swz(i >> 3) << 3) | (i & 7);
        xsH[pos] = h; xsL[pos] = l;
    }
    __syncthreads();

    const int nb = wid * 64;
    f4v acc[2][4];
#pragma unroll
    for (int mt = 0; mt < 2; ++mt)
#pragma unroll
        for (int nt = 0; nt < 4; ++nt) acc[mt][nt] = (f4v)0.0f;

    for (int kt = 0; kt < 8; ++kt) {
        s8v aH[2], aL[2];
#pragma unroll
        for (int mt = 0; mt < 2; ++mt) {
            int row = mt * 16 + m;
            int su = swz(row * 8 + kt * 4 + q) << 3;
            aH[mt] = *(const s8v*)&xsH[su];
            aL[mt] = *(const s8v*)&xsL[su];
        }
        s8v bH[4], bL[4];
#pragma unroll
        for (int nt = 0; nt < 4; ++nt) {
            size_t bi = ((size_t)(kt * 4 + q) * 256 + nb + nt * 16 + m) * 8;
            bH[nt] = *(const s8v*)(wFH + bi);
            bL[nt] = *(const s8v*)(wFL + bi);
        }
#pragma unroll
        for (int mt = 0; mt < 2; ++mt)
#pragma unroll
            for (int nt = 0; nt < 4; ++nt)
                acc[mt][nt] = MFMA16(aH[mt], bH[nt], acc[mt][nt]);
#pragma unroll
        for (int mt = 0; mt < 2; ++mt)
#pragma unroll
            for (int nt = 0; nt < 4; ++nt)
                acc[mt][nt] = MFMA16(aL[mt], bH[nt], acc[mt][nt]);
#pragma unroll
        for (int mt = 0; mt < 2; ++mt)
#pragma unroll
            for (int nt = 0; nt < 4; ++nt)
                acc[mt][nt] = MFMA16(aH[mt], bL[nt], acc[mt][nt]);
    }
    __syncthreads();

#pragma unroll
    for (int mt = 0; mt < 2; ++mt)
#pragma unroll
        for (int nt = 0; nt < 4; ++nt) {
            int d = nb + nt * 16 + m;
            float bias = conv_b[d];
#pragma unroll
            for (int r = 0; r < 4; ++r) {
                int row = mt * 16 + q * 4 + r;
                float v = fmaxf(acc[mt][nt][r] + bias, 0.0f);
                short h, l; split2(v, h, l);
                int dd = d ^ ((row & 7) << 3);
                hidH[row * 256 + dd] = h;
                hidL[row * 256 + dd] = l;
            }
        }
    __syncthreads();

    const int pb = wid * 16;
    const int sw0 = (m & 7) << 3;
    f4v aHH[2], aLH[2], aHL[2];
#pragma unroll
    for (int mt = 0; mt < 2; ++mt) {
        aHH[mt] = (f4v)0.0f; aLH[mt] = (f4v)0.0f; aHL[mt] = (f4v)0.0f;
    }
    for (int kt = 0; kt < 8; ++kt) {
        s8v aH[2], aL[2];
#pragma unroll
        for (int mt = 0; mt < 2; ++mt) {
            int off = (mt * 16 + m) * 256 + ((kt * 32 + q * 8) ^ sw0);
            aH[mt] = *(const s8v*)&hidH[off];
            aL[mt] = *(const s8v*)&hidL[off];
        }
        size_t bi = ((size_t)(kt * 4 + q) * 64 + pb + m) * 8;
        s8v bH = *(const s8v*)(kFH + bi);
        s8v bL = *(const s8v*)(kFL + bi);
#pragma unroll
        for (int mt = 0; mt < 2; ++mt)
            aHH[mt] = MFMA16(aH[mt], bH, aHH[mt]);
#pragma unroll
        for (int mt = 0; mt < 2; ++mt)
            aLH[mt] = MFMA16(aL[mt], bH, aLH[mt]);
#pragma unroll
        for (int mt = 0; mt < 2; ++mt)
            aHL[mt] = MFMA16(aH[mt], bL, aHL[mt]);
    }
#pragma unroll
    for (int mt = 0; mt < 2; ++mt) {
        f4v s = aHH[mt] + aLH[mt] + aHL[mt];
        f4v st;
        st[0] = fminf(fmaxf(s[0], 0.0f), 6.0f) * LOG2E;
        st[1] = fminf(fmaxf(s[1], 0.0f), 6.0f) * LOG2E;
        st[2] = fminf(fmaxf(s[2], 0.0f), 6.0f) * LOG2E;
        st[3] = fminf(fmaxf(s[3], 0.0f), 6.0f) * LOG2E;
        store4_llc(&scoresT[((size_t)b * NPAT + pb + m) * TS + t0 + mt * 16 + q * 4],
                   st);
    }
    drain_stores();            // this wave's LLC stores acked
    __syncthreads();           // all waves drained
    if (tid == 0)
        store1_llc(&flags[b * NCH + (t0 >> 5)], 1u);
}

// ================= mixed grid: 128 scan/signal blocks + 8192 scores blocks ====
__launch_bounds__(256, 4)
__global__ void fused(const float* __restrict__ x,
                      const short* __restrict__ wFH, const short* __restrict__ wFL,
                      const short* __restrict__ kFH, const short* __restrict__ kFL,
                      const short* __restrict__ sFH, const short* __restrict__ sFL,
                      const float* __restrict__ conv_b,
                      const float* __restrict__ avg0,
                      float* __restrict__ scoresT,
                      unsigned* __restrict__ flags,
                      float* __restrict__ out) {
    __shared__ __align__(16) short smem[16384];    // 32 KB, both roles

    if (blockIdx.x >= 128) {
        const int sid = blockIdx.x - 128;
        const int tb = sid >> 8;           // tb-major: all batches' tb=0 first
        const int b = sid & 255;
        scores_role(smem, b, tb * 32, x, wFH, wFL, kFH, kFL, conv_b, scoresT, flags);
        return;
    }

    const int blk = blockIdx.x;            // 0..127
    const int bA = 2 * blk, bB = 2 * blk + 1;
    const int tid = threadIdx.x;
    const int wid = tid >> 6, lane = tid & 63;
    short* pbAH = smem;                    // [2][CH][64] each
    short* pbAL = smem + 4096;
    short* pbBH = smem + 8192;
    short* pbBL = smem + 12288;

    if (wid == 0) {
        // ---------- dual scan wave (R8 math verbatim; depth-2 prefetch) ----------
        // scoresT refills are plain cached loads: lines are first-touched only
        // AFTER the producing flag is confirmed (L2 invalidated at dispatch,
        // producer wrote through to LLC) -> fresh data, no invalidate needed.
        const int p = lane;
        const float4* sA = (const float4*)(scoresT + ((size_t)bA * NPAT + p) * TS);
        const float4* sB = (const float4*)(scoresT + ((size_t)bB * NPAT + p) * TS);
        float avgA = avg0[bA * NPAT + p] * LOG2E;
        float avgB = avg0[bB * NPAT + p] * LOG2E;
        const float invc = LOG2E / NPAT;

        wait2(&flags[bA * NCH], &flags[bB * NCH], lane);
        float4 bufA[2], bufB[2];
#pragma unroll
        for (int s = 0; s < 2; ++s) { bufA[s] = sA[s]; bufB[s] = sB[s]; }

        for (int c = 0; c < NCH; ++c) {
            if (c + 1 < NCH)
                wait2(&flags[bA * NCH + c + 1], &flags[bB * NCH + c + 1], lane);
            short* bHA = pbAH + (c & 1) * SLOT;
            short* bLA = pbAL + (c & 1) * SLOT;
            short* bHB = pbBH + (c & 1) * SLOT;
            short* bLB = pbBL + (c & 1) * SLOT;
            for (int kb = 0; kb < 8; kb += 2) {
#pragma unroll
                for (int s = 0; s < 2; ++s) {
                    const int g = c * 8 + kb + s;
                    float4 vA = bufA[s], vB = bufB[s];
                    float* a = (float*)&vA;
                    float* bv = (float*)&vB;
#pragma unroll
                    for (int j = 0; j < 4; ++j) {
                        float eA = exp2f(a[j] - avgA);
                        float eB = exp2f(bv[j] - avgB);
                        float wA = eA, wB = eB;
                        wA = dppadd<0x111>(wA); wB = dppadd<0x111>(wB);
                        wA = dppadd<0x112>(wA); wB = dppadd<0x112>(wB);
                        wA = dppadd<0x114>(wA); wB = dppadd<0x114>(wB);
                        wA = dppadd<0x118>(wA); wB = dppadd<0x118>(wB);
                        wA = dppadd<0x142>(wA); wB = dppadd<0x142>(wB);
                        wA = dppadd<0x143>(wA); wB = dppadd<0x143>(wB);
                        float tA = __int_as_float(
                            __builtin_amdgcn_readlane(__float_as_int(wA), 63));
                        float tB = __int_as_float(
                            __builtin_amdgcn_readlane(__float_as_int(wB), 63));
                        float prA = eA * __builtin_amdgcn_rcpf(tA);
                        float prB = eB * __builtin_amdgcn_rcpf(tB);
                        avgA = __builtin_fmaf(prA, LOG2E, avgA - invc);
                        avgB = __builtin_fmaf(prB, LOG2E, avgB - invc);
                        const int trow = (kb + s) * 4 + j;
                        const int col = p ^ ((trow & 7) << 3);
                        short h, l;
                        split2(prA, h, l);
                        bHA[trow * 64 + col] = h;
                        bLA[trow * 64 + col] = l;
                        split2(prB, h, l);
                        bHB[trow * 64 + col] = h;
                        bLB[trow * 64 + col] = l;
                    }
                    if (g + 2 < TS / 4) {      // depth-2 refill; flag c+1 confirmed
                        bufA[s] = sA[g + 2];
                        bufB[s] = sB[g + 2];
                    }
                }
            }
            __syncthreads();   // chunk c published
        }
        __syncthreads();       // cover consumers' last chunk
    } else if (wid <= 2) {
        // ---------- signal consumer wave (one batch) ----------
        const int b = (wid == 1) ? bA : bB;
        const short* rbH = (wid == 1) ? pbAH : pbBH;
        const short* rbL = (wid == 1) ? pbAL : pbBL;
        const int m = lane & 15, q = lane >> 4;
        const float* xb = x + (size_t)b * LL;
        float* ob = out + (size_t)b * LL;

        __syncthreads();       // wave 0 filling chunk 0
        for (int cc = 0; cc < NCH; ++cc) {
            const short* pH = rbH + (cc & 1) * SLOT;
            const short* pL = rbL + (cc & 1) * SLOT;
            const int t0 = cc * CH;
#pragma unroll
            for (int mt = 0; mt < 2; ++mt) {
                float xv[4][4];
#pragma unroll
                for (int nt = 0; nt < 4; ++nt)
#pragma unroll
                    for (int r = 0; r < 4; ++r)
                        xv[nt][r] = xb[(size_t)(t0 + mt * 16 + q * 4 + r) * WINW +
                                       nt * 16 + m];
                f4v acc[4];
#pragma unroll
                for (int nt = 0; nt < 4; ++nt) acc[nt] = (f4v)0.0f;
#pragma unroll
                for (int kt = 0; kt < 2; ++kt) {
                    const int rr = mt * 16 + m;
                    const int col = (kt * 32 + q * 8) ^ ((m & 7) << 3);
                    s8v aH = *(const s8v*)&pH[rr * 64 + col];
                    s8v aL = *(const s8v*)&pL[rr * 64 + col];
#pragma unroll
                    for (int nt = 0; nt < 4; ++nt) {
                        size_t bi = ((size_t)(kt * 4 + q) * 64 + nt * 16 + m) * 8;
                        s8v bH = *(const s8v*)(sFH + bi);
                        s8v bL = *(const s8v*)(sFL + bi);
                        acc[nt] = MFMA16(aH, bH, acc[nt]);
                        acc[nt] = MFMA16(aL, bH, acc[nt]);
                        acc[nt] = MFMA16(aH, bL, acc[nt]);
                    }
                }
#pragma unroll
                for (int nt = 0; nt < 4; ++nt)
#pragma unroll
                    for (int r = 0; r < 4; ++r) {
                        size_t gi = (size_t)(t0 + mt * 16 + q * 4 + r) * WINW +
                                    nt * 16 + m;
                        ob[gi] = fmaxf(acc[nt][r] - xv[nt][r], 0.0f);
                    }
            }
            __syncthreads();   // ring slot free
        }
    } else {
        // ---------- barrier matcher (wave 3) ----------
        for (int i = 0; i < NCH + 1; ++i) __syncthreads();
    }
}

extern "C" void kernel_launch(void* const* d_in, const int* in_sizes, int n_in,
                              void* d_out, int out_size, void* d_ws, size_t ws_size,
                              hipStream_t stream) {
    const float* x      = (const float*)d_in[0];
    const float* avg0   = (const float*)d_in[1];
    const float* conv_w = (const float*)d_in[2];
    const float* conv_b = (const float*)d_in[3];
    const float* keys   = (const float*)d_in[4];
    const float* shapes = (const float*)d_in[5];
    float* out = (float*)d_out;

    char* ws = (char*)d_ws;
    size_t o = 0;
    float* scoresT = (float*)(ws + o); o += (size_t)BB * TS * NPAT * 4;   // 64 MB
    short* wFH = (short*)(ws + o); o += 8192 * 16;
    short* wFL = (short*)(ws + o); o += 8192 * 16;
    short* kFH = (short*)(ws + o); o += 2048 * 16;
    short* kFL = (short*)(ws + o); o += 2048 * 16;
    short* sFH = (short*)(ws + o); o += 512 * 16;
    short* sFL = (short*)(ws + o); o += 512 * 16;
    unsigned* flags = (unsigned*)(ws + o); o += (size_t)BB * NCH * 4;     // 32 KB

    (void)hipMemsetAsync(flags, 0, (size_t)BB * NCH * 4, stream);
    prep_all<<<42, 256, 0, stream>>>(conv_w, wFH, wFL, keys, kFH, kFL, shapes, sFH, sFL);
    fused<<<dim3(128 + 32 * BB), 256, 0, stream>>>(x, wFH, wFL, kFH, kFL, sFH, sFL,
                                                   conv_b, avg0, scoresT, flags, out);
}

// Round 12
// 359.595 us; speedup vs baseline: 4.6519x; 1.2477x over previous
//
#include <hip/hip_runtime.h>

#define BB 256
#define LL 65536
#define TS 1024
#define HIST 256
#define WINW 64
#define DIM 256
#define NPAT 64

typedef short s8v __attribute__((ext_vector_type(8)));
typedef float f4v __attribute__((ext_vector_type(4)));

#define MFMA16(a, b, c) __builtin_amdgcn_mfma_f32_16x16x32_bf16((a), (b), (c), 0, 0, 0)
#define LOG2E 1.44269504f

// ---- fp32 -> bf16 hi/lo split (combined error ~2^-18 relative) ----
__device__ __forceinline__ short bf16rne(float f) {
    unsigned u = __float_as_uint(f);
    unsigned r = (u + 0x7fffu + ((u >> 16) & 1u)) >> 16;
    return (short)r;
}
__device__ __forceinline__ float bf16tof(short h) {
    return __uint_as_float(((unsigned)(unsigned short)h) << 16);
}
__device__ __forceinline__ void split2(float f, short& hi, short& lo) {
    hi = bf16rne(f);
    lo = bf16rne(f - bf16tof(hi));
}

// ---- merged prep: conv_w / keys / shapes -> hi/lo MFMA B-fragments ----
__global__ void prep_all(const float* __restrict__ w, short* __restrict__ wFH,
                         short* __restrict__ wFL,
                         const float* __restrict__ keys, short* __restrict__ kFH,
                         short* __restrict__ kFL,
                         const float* __restrict__ sh, short* __restrict__ sFH,
                         short* __restrict__ sFL) {
    int bid = blockIdx.x;
    s8v hv, lv;
    if (bid < 32) {
        int idx = bid * 256 + threadIdx.x;        // 8192 = 32 qk * 256 d
        int d = idx & 255, qk = idx >> 8;
        int h0 = qk * 8;
#pragma unroll
        for (int j = 0; j < 8; ++j) {
            short h, l; split2(w[d * HIST + h0 + j], h, l);
            hv[j] = h; lv[j] = l;
        }
        *(s8v*)(wFH + (size_t)idx * 8) = hv;
        *(s8v*)(wFL + (size_t)idx * 8) = lv;
    } else if (bid < 40) {
        int idx = (bid - 32) * 256 + threadIdx.x; // 2048 = 32 qk * 64 p
        int p = idx & 63, qk = idx >> 6;
        int d0 = qk * 8;
#pragma unroll
        for (int j = 0; j < 8; ++j) {
            short h, l; split2(keys[(d0 + j) * NPAT + p], h, l);
            hv[j] = h; lv[j] = l;
        }
        *(s8v*)(kFH + (size_t)idx * 8) = hv;
        *(s8v*)(kFL + (size_t)idx * 8) = lv;
    } else {
        int idx = (bid - 40) * 256 + threadIdx.x; // 512 = 8 qk * 64 w
        int ww = idx & 63, qk = idx >> 6;
        int p0 = qk * 8;
#pragma unroll
        for (int j = 0; j < 8; ++j) {
            short h, l; split2(sh[(p0 + j) * WINW + ww], h, l);
            hv[j] = h; lv[j] = l;
        }
        *(s8v*)(sFH + (size_t)idx * 8) = hv;
        *(s8v*)(sFL + (size_t)idx * 8) = lv;
    }
}

#define WELEM 2240           // 31*64 + 256 window elements

__device__ __forceinline__ int swz(int u) { return u ^ ((u >> 3) & 7); }

// ---- fused conv + relu + (hid @ keys) + relu6; scoresT[b][p][t] pre-scaled by log2e ----
// R2-measured-good: 163-177 us, (256,4), xs aliases hid, 32KB LDS.
__launch_bounds__(256, 4)
__global__ void scores_mfma(const float* __restrict__ x,
                            const short* __restrict__ wFH, const short* __restrict__ wFL,
                            const short* __restrict__ kFH, const short* __restrict__ kFL,
                            const float* __restrict__ conv_b,
                            float* __restrict__ scoresT) {
    __shared__ __align__(16) short hidH[32 * 256], hidL[32 * 256];   // 16 KB each
    short* xsH = hidH;   // alias: first WELEM*2 bytes, dead after phase 1
    short* xsL = hidL;

    const int b = blockIdx.y, t0 = blockIdx.x * 32;
    const int tid = threadIdx.x;
    const int lane = tid & 63, wid = tid >> 6;
    const int m = lane & 15, q = lane >> 4;

    const float* xb = x + (size_t)b * LL;
    const int gbase = t0 * WINW - (HIST - 1);
    for (int i = tid; i < WELEM; i += 256) {
        int gi = gbase + i;
        float v = (gi >= 0) ? xb[gi] : 0.0f;
        short h, l; split2(v, h, l);
        int pos = (swz(i >> 3) << 3) | (i & 7);
        xsH[pos] = h; xsL[pos] = l;
    }
    __syncthreads();

    // Phase 1: conv GEMM. Wave wid owns d-range [wid*64, +64). Term-major order.
    const int nb = wid * 64;
    f4v acc[2][4];
#pragma unroll
    for (int mt = 0; mt < 2; ++mt)
#pragma unroll
        for (int nt = 0; nt < 4; ++nt) acc[mt][nt] = (f4v)0.0f;

    for (int kt = 0; kt < 8; ++kt) {
        s8v aH[2], aL[2];
#pragma unroll
        for (int mt = 0; mt < 2; ++mt) {
            int row = mt * 16 + m;
            int su = swz(row * 8 + kt * 4 + q) << 3;
            aH[mt] = *(const s8v*)&xsH[su];
            aL[mt] = *(const s8v*)&xsL[su];
        }
        s8v bH[4], bL[4];
#pragma unroll
        for (int nt = 0; nt < 4; ++nt) {
            size_t bi = ((size_t)(kt * 4 + q) * 256 + nb + nt * 16 + m) * 8;
            bH[nt] = *(const s8v*)(wFH + bi);
            bL[nt] = *(const s8v*)(wFL + bi);
        }
#pragma unroll
        for (int mt = 0; mt < 2; ++mt)
#pragma unroll
            for (int nt = 0; nt < 4; ++nt)
                acc[mt][nt] = MFMA16(aH[mt], bH[nt], acc[mt][nt]);
#pragma unroll
        for (int mt = 0; mt < 2; ++mt)
#pragma unroll
            for (int nt = 0; nt < 4; ++nt)
                acc[mt][nt] = MFMA16(aL[mt], bH[nt], acc[mt][nt]);
#pragma unroll
        for (int mt = 0; mt < 2; ++mt)
#pragma unroll
            for (int nt = 0; nt < 4; ++nt)
                acc[mt][nt] = MFMA16(aH[mt], bL[nt], acc[mt][nt]);
    }
    __syncthreads();   // all xs reads done -> hid may overwrite the union

    // Epilogue 1: bias + relu -> hid (bf16 hi/lo, XOR-swizzled rows)
#pragma unroll
    for (int mt = 0; mt < 2; ++mt)
#pragma unroll
        for (int nt = 0; nt < 4; ++nt) {
            int d = nb + nt * 16 + m;
            float bias = conv_b[d];
#pragma unroll
            for (int r = 0; r < 4; ++r) {
                int row = mt * 16 + q * 4 + r;
                float v = fmaxf(acc[mt][nt][r] + bias, 0.0f);
                short h, l; split2(v, h, l);
                int dd = d ^ ((row & 7) << 3);      // XOR swizzle, 8-elem granularity
                hidH[row * 256 + dd] = h;
                hidL[row * 256 + dd] = l;
            }
        }
    __syncthreads();

    // Phase 2: scores GEMM (K=256 over d). Per-term accumulators (6 chains).
    const int pb = wid * 16;
    const int sw0 = (m & 7) << 3;
    f4v aHH[2], aLH[2], aHL[2];
#pragma unroll
    for (int mt = 0; mt < 2; ++mt) {
        aHH[mt] = (f4v)0.0f; aLH[mt] = (f4v)0.0f; aHL[mt] = (f4v)0.0f;
    }
    for (int kt = 0; kt < 8; ++kt) {
        s8v aH[2], aL[2];
#pragma unroll
        for (int mt = 0; mt < 2; ++mt) {
            int off = (mt * 16 + m) * 256 + ((kt * 32 + q * 8) ^ sw0);
            aH[mt] = *(const s8v*)&hidH[off];
            aL[mt] = *(const s8v*)&hidL[off];
        }
        size_t bi = ((size_t)(kt * 4 + q) * 64 + pb + m) * 8;
        s8v bH = *(const s8v*)(kFH + bi);
        s8v bL = *(const s8v*)(kFL + bi);
#pragma unroll
        for (int mt = 0; mt < 2; ++mt)
            aHH[mt] = MFMA16(aH[mt], bH, aHH[mt]);
#pragma unroll
        for (int mt = 0; mt < 2; ++mt)
            aLH[mt] = MFMA16(aL[mt], bH, aLH[mt]);
#pragma unroll
        for (int mt = 0; mt < 2; ++mt)
            aHL[mt] = MFMA16(aH[mt], bL, aHL[mt]);
    }
#pragma unroll
    for (int mt = 0; mt < 2; ++mt) {
        f4v s = aHH[mt] + aLH[mt] + aHL[mt];
        float4 st;
        st.x = fminf(fmaxf(s[0], 0.0f), 6.0f) * LOG2E;
        st.y = fminf(fmaxf(s[1], 0.0f), 6.0f) * LOG2E;
        st.z = fminf(fmaxf(s[2], 0.0f), 6.0f) * LOG2E;
        st.w = fminf(fmaxf(s[3], 0.0f), 6.0f) * LOG2E;
        *(float4*)&scoresT[((size_t)b * NPAT + pb + m) * TS + t0 + mt * 16 + q * 4] = st;
    }
}

template <int CTRL>
__device__ __forceinline__ float dppadd(float x) {
    int t = __builtin_amdgcn_update_dpp(0, __float_as_int(x), CTRL, 0xf, 0xf, true);
    return x + __int_as_float(t);
}

// ---- fused dual scan + signal: 128 blocks x 192 threads ----
// wave 0: TWO interleaved softmax-scan chains (batches 2k, 2k+1). R12 change: the
//         scan stores raw fp32 pr (one ds_write_b32/step/batch, swizzled [t][p]) —
//         split2 moved to the consumer waves, which idle ~80% of each chunk.
//         Removes ~16 instr/dual-step from the issue-bound scan wave.
// wave 1: signal MFMA consumer for batch A;  wave 2: same for batch B.
// Consumers load 8 fp32 (two aligned f4v, 2-way bank alias = free) and split there.
// Output bit-identical: split2(pr) on the same fp32 pr bits, different wave.
#define CH 32
#define NCH (TS / CH)
#define FSLOT (CH * 64)      // floats per ring slot

__launch_bounds__(192, 1)
__global__ void scan_signal2(const float* __restrict__ scoresT,
                             const float* __restrict__ avg0,
                             const short* __restrict__ sFH, const short* __restrict__ sFL,
                             const float* __restrict__ x,
                             float* __restrict__ out) {
    __shared__ __align__(16) float pA[2 * FSLOT], pB[2 * FSLOT];   // 8KB+8KB per batch

    const int blk = blockIdx.x;            // 0..127
    const int bA = 2 * blk, bB = 2 * blk + 1;
    const int tid = threadIdx.x;
    const int wid = tid >> 6, lane = tid & 63;

    if (wid == 0) {
        // ================= dual scan wave =================
        const int p = lane;
        const float4* sA = (const float4*)(scoresT + ((size_t)bA * NPAT + p) * TS);
        const float4* sB = (const float4*)(scoresT + ((size_t)bB * NPAT + p) * TS);
        float avgA = avg0[bA * NPAT + p] * LOG2E;
        float avgB = avg0[bB * NPAT + p] * LOG2E;
        const float invc = LOG2E / NPAT;

        float4 bufA[4], bufB[4];
#pragma unroll
        for (int s = 0; s < 4; ++s) { bufA[s] = sA[s]; bufB[s] = sB[s]; }

        for (int c = 0; c < NCH; ++c) {
            float* dA = pA + (c & 1) * FSLOT;
            float* dB = pB + (c & 1) * FSLOT;
            for (int kb = 0; kb < 8; kb += 4) {
#pragma unroll
                for (int s = 0; s < 4; ++s) {
                    const int g = c * 8 + kb + s;
                    float4 vA = bufA[s], vB = bufB[s];
                    float* a = (float*)&vA;
                    float* bv = (float*)&vB;
#pragma unroll
                    for (int j = 0; j < 4; ++j) {
                        float eA = exp2f(a[j] - avgA);
                        float eB = exp2f(bv[j] - avgB);
                        float wA = eA, wB = eB;
                        wA = dppadd<0x111>(wA); wB = dppadd<0x111>(wB);   // row_shr:1
                        wA = dppadd<0x112>(wA); wB = dppadd<0x112>(wB);   // row_shr:2
                        wA = dppadd<0x114>(wA); wB = dppadd<0x114>(wB);   // row_shr:4
                        wA = dppadd<0x118>(wA); wB = dppadd<0x118>(wB);   // row_shr:8
                        wA = dppadd<0x142>(wA); wB = dppadd<0x142>(wB);   // row_bcast:15
                        wA = dppadd<0x143>(wA); wB = dppadd<0x143>(wB);   // row_bcast:31
                        float tA = __int_as_float(
                            __builtin_amdgcn_readlane(__float_as_int(wA), 63));
                        float tB = __int_as_float(
                            __builtin_amdgcn_readlane(__float_as_int(wB), 63));
                        float prA = eA * __builtin_amdgcn_rcpf(tA);
                        float prB = eB * __builtin_amdgcn_rcpf(tB);
                        avgA = __builtin_fmaf(prA, LOG2E, avgA - invc);
                        avgB = __builtin_fmaf(prB, LOG2E, avgB - invc);
                        const int trow = (kb + s) * 4 + j;
                        const int col = p ^ ((trow & 7) << 3);   // bank-free permutation
                        dA[trow * 64 + col] = prA;
                        dB[trow * 64 + col] = prB;
                    }
                    if (g + 4 < TS / 4) {          // deep-in-flight refill
                        bufA[s] = sA[g + 4];
                        bufB[s] = sB[g + 4];
                    }
                }
            }
            __syncthreads();   // chunk c published to both rings
        }
        __syncthreads();       // cover consumers' last chunk
    } else {
        // ================= signal consumer wave (one batch) =================
        const int b = (wid == 1) ? bA : bB;
        const float* ring = (wid == 1) ? pA : pB;
        const int m = lane & 15, q = lane >> 4;

        s8v sbH[2][4], sbL[2][4];
#pragma unroll
        for (int kt = 0; kt < 2; ++kt)
#pragma unroll
            for (int nt = 0; nt < 4; ++nt) {
                size_t bi = ((size_t)(kt * 4 + q) * 64 + nt * 16 + m) * 8;
                sbH[kt][nt] = *(const s8v*)(sFH + bi);
                sbL[kt][nt] = *(const s8v*)(sFL + bi);
            }
        const float* xb = x + (size_t)b * LL;
        float* ob = out + (size_t)b * LL;

        __syncthreads();       // wave 0 filling chunk 0
        for (int cc = 0; cc < NCH; ++cc) {
            const float* pF = ring + (cc & 1) * FSLOT;
            const int t0 = cc * CH;
#pragma unroll
            for (int mt = 0; mt < 2; ++mt) {
                float xv[4][4];
#pragma unroll
                for (int nt = 0; nt < 4; ++nt)
#pragma unroll
                    for (int r = 0; r < 4; ++r)
                        xv[nt][r] = xb[(size_t)(t0 + mt * 16 + q * 4 + r) * WINW +
                                       nt * 16 + m];
                f4v acc[4];
#pragma unroll
                for (int nt = 0; nt < 4; ++nt) acc[nt] = (f4v)0.0f;
#pragma unroll
                for (int kt = 0; kt < 2; ++kt) {
                    const int rr = mt * 16 + m;
                    const int col = (kt * 32 + q * 8) ^ ((rr & 7) << 3);
                    const float* src = pF + rr * 64 + col;       // 32B-aligned octet
                    f4v v0 = *(const f4v*)src;
                    f4v v1 = *(const f4v*)(src + 4);
                    s8v aH, aL;
#pragma unroll
                    for (int j = 0; j < 4; ++j) {
                        short h, l;
                        split2(v0[j], h, l); aH[j] = h; aL[j] = l;
                        split2(v1[j], h, l); aH[4 + j] = h; aL[4 + j] = l;
                    }
#pragma unroll
                    for (int nt = 0; nt < 4; ++nt) {
                        acc[nt] = MFMA16(aH, sbH[kt][nt], acc[nt]);
                        acc[nt] = MFMA16(aL, sbH[kt][nt], acc[nt]);
                        acc[nt] = MFMA16(aH, sbL[kt][nt], acc[nt]);
                    }
                }
#pragma unroll
                for (int nt = 0; nt < 4; ++nt)
#pragma unroll
                    for (int r = 0; r < 4; ++r) {
                        size_t gi = (size_t)(t0 + mt * 16 + q * 4 + r) * WINW +
                                    nt * 16 + m;
                        ob[gi] = fmaxf(acc[nt][r] - xv[nt][r], 0.0f);
                    }
            }
            __syncthreads();   // ring slot free for producer
        }
    }
}

extern "C" void kernel_launch(void* const* d_in, const int* in_sizes, int n_in,
                              void* d_out, int out_size, void* d_ws, size_t ws_size,
                              hipStream_t stream) {
    const float* x      = (const float*)d_in[0];
    const float* avg0   = (const float*)d_in[1];
    const float* conv_w = (const float*)d_in[2];
    const float* conv_b = (const float*)d_in[3];
    const float* keys   = (const float*)d_in[4];
    const float* shapes = (const float*)d_in[5];
    float* out = (float*)d_out;

    char* ws = (char*)d_ws;
    size_t o = 0;
    float* scoresT = (float*)(ws + o); o += (size_t)BB * TS * NPAT * 4;   // 64 MB
    short* wFH = (short*)(ws + o); o += 8192 * 16;
    short* wFL = (short*)(ws + o); o += 8192 * 16;
    short* kFH = (short*)(ws + o); o += 2048 * 16;
    short* kFL = (short*)(ws + o); o += 2048 * 16;
    short* sFH = (short*)(ws + o); o += 512 * 16;
    short* sFL = (short*)(ws + o); o += 512 * 16;

    prep_all<<<42, 256, 0, stream>>>(conv_w, wFH, wFL, keys, kFH, kFL, shapes, sFH, sFL);
    scores_mfma<<<dim3(TS / 32, BB), 256, 0, stream>>>(x, wFH, wFL, kFH, kFL, conv_b, scoresT);
    scan_signal2<<<dim3(BB / 2), 192, 0, stream>>>(scoresT, avg0, sFH, sFL, x, out);
}